// Round 9
// baseline (154.291 us; speedup 1.0000x reference)
//
#include <hip/hip_runtime.h>

#define B_DIM 32
#define C_DIM 64
#define D_DIM 64
#define T_DIM 30000
#define T4    7500
#define JTILE 128                 // j columns per mix tile
#define TILES 235                 // ceil(30000 / 128)
#define NWG   (TILES * B_DIM)     // 7520, divisible by 8
#define ROWS  (B_DIM * C_DIM)     // 2048

typedef short bf16x8 __attribute__((ext_vector_type(8)));
typedef float f32x16 __attribute__((ext_vector_type(16)));
typedef float f32x4  __attribute__((ext_vector_type(4)));

__device__ __forceinline__ unsigned short f32_to_bf16_rne(float f) {
    unsigned int u = __builtin_bit_cast(unsigned int, f);
    return (unsigned short)((u + 0x7fffu + ((u >> 16) & 1u)) >> 16);
}

// ---------------- Kernel A: desc[b,c] = mean over T (R5 exact) ----------------
__global__ __launch_bounds__(256) void mean_kernel(const float* __restrict__ x,
                                                   float* __restrict__ desc) {
    int r = blockIdx.x;  // b*64 + c
    const float4* xr = (const float4*)(x + (size_t)r * T_DIM);
    float4 s = {0.f, 0.f, 0.f, 0.f};
    for (int i = threadIdx.x; i < T4; i += 256) {
        float4 v = xr[i];
        s.x += v.x; s.y += v.y; s.z += v.z; s.w += v.w;
    }
    float p = (s.x + s.y) + (s.z + s.w);
    #pragma unroll
    for (int off = 32; off > 0; off >>= 1) p += __shfl_down(p, off, 64);
    __shared__ float wsum[4];
    int wave = threadIdx.x >> 6;
    int lane = threadIdx.x & 63;
    if (lane == 0) wsum[wave] = p;
    __syncthreads();
    if (threadIdx.x == 0) {
        float tot = (wsum[0] + wsum[1]) + (wsum[2] + wsum[3]);
        desc[r] = tot * (1.0f / (float)T_DIM);
    }
}

// ---------------- Kernel B: attn2 = bf16(alpha * softmax(logits) + I) ----------------
__global__ __launch_bounds__(64) void attn_kernel(const float* __restrict__ desc,
                                                  const float* __restrict__ Wq,
                                                  const float* __restrict__ bq,
                                                  const float* __restrict__ Wk,
                                                  const float* __restrict__ bk,
                                                  const float* __restrict__ alphap,
                                                  unsigned short* __restrict__ attnb) {
    int b = blockIdx.x;
    int c = threadIdx.x;
    __shared__ float sd[C_DIM];
    sd[c] = desc[b * C_DIM + c];
    __syncthreads();

    float dA = 0.f, dBq = 0.f, dBk = 0.f, dCc = 0.f;
    #pragma unroll
    for (int d = 0; d < D_DIM; ++d) {
        float wq = Wq[d], wk = Wk[d], vq = bq[d], vk = bk[d];
        dA  += wq * wk;
        dBq += wq * vk;
        dBk += vq * wk;
        dCc += vq * vk;
    }

    float dc = sd[c];
    float l[C_DIM];
    float lmax = -1e30f;
    #pragma unroll
    for (int e = 0; e < C_DIM; ++e) {
        float de = sd[e];
        float v = (dA * dc * de + dBq * dc + dBk * de + dCc) * 0.125f;
        l[e] = v;
        lmax = fmaxf(lmax, v);
    }
    float sum = 0.f;
    #pragma unroll
    for (int e = 0; e < C_DIM; ++e) {
        float ev = __expf(l[e] - lmax);
        l[e] = ev;
        sum += ev;
    }
    float inv = alphap[0] / sum;   // fold alpha
    unsigned short* arow = attnb + ((size_t)b * C_DIM + c) * C_DIM;
    #pragma unroll
    for (int e = 0; e < C_DIM; ++e) {
        float v = l[e] * inv + (e == c ? 1.0f : 0.0f);  // fold residual
        arow[e] = f32_to_bf16_rne(v);
    }
}

// ---------------- Kernel C: out = attn2 @ x via bf16 MFMA, LDS-staged ----------------
// R5 structure + two isolated levers:
//   (1) reversed tile order (hot-first: mean leaves high-t x L3-hottest; all
//       XCDs consume tile 234 at the same wall-time -> global desc-recency)
//   (2) non-temporal x staging loads (misses don't allocate -> out-writes are
//       the only L3 pressure during mix, preserving resident x longer)
__global__ __launch_bounds__(256) void mix_mfma(const float* __restrict__ x,
                                                const unsigned short* __restrict__ attnb,
                                                float* __restrict__ out) {
    __shared__ float lx[C_DIM][JTILE];   // 32 KB; x-tile, then out-tile

    int flat = blockIdx.x;
    int swz  = (flat & 7) * (NWG / 8) + (flat >> 3);
    int b    = swz / TILES;
    int tile = (TILES - 1) - (swz % TILES);   // reversed: hottest t first

    int t   = threadIdx.x;
    int w   = t >> 6;
    int l31 = t & 31;
    int lhi = (t >> 5) & 1;

    // ---- A fragments (attn2, bf16) — issue first, fly under the staging barrier
    const unsigned short* ab = attnb + (size_t)b * C_DIM * C_DIM;
    bf16x8 afrag[2][4];
    #pragma unroll
    for (int m = 0; m < 2; ++m)
        #pragma unroll
        for (int g = 0; g < 4; ++g)
            afrag[m][g] = *(const bf16x8*)(ab + (32 * m + l31) * C_DIM + 16 * g + 8 * lhi);

    // ---- stage x tile: 8 coalesced nt float4 loads -> ds_write_b128
    const float* xbp = x + (size_t)b * C_DIM * T_DIM;
    int cf4  = t & 31;                 // float4 col within tile
    int jf4  = tile * 32 + cf4;        // global float4 col
    int jf4c = (jf4 < T4) ? jf4 : (T4 - 1);
    #pragma unroll
    for (int p = 0; p < 8; ++p) {
        int e = p * 8 + (t >> 5);
        f32x4 v = __builtin_nontemporal_load(
            (const f32x4*)(xbp + (size_t)e * T_DIM + (size_t)jf4c * 4));
        *(f32x4*)&lx[e][cf4 * 4] = v;
    }
    __syncthreads();

    // ---- compute: B-frags from LDS (conflict-free ds_read_b32), cvt, MFMA
    int jc = w * 32 + l31;             // this lane's j col within tile
    f32x16 acc0 = {}, acc1 = {};
    #pragma unroll
    for (int g = 0; g < 4; ++g) {
        int e0 = 16 * g + 8 * lhi;
        bf16x8 bfrag;
        #pragma unroll
        for (int i = 0; i < 8; ++i)
            bfrag[i] = (short)f32_to_bf16_rne(lx[e0 + i][jc]);
        acc0 = __builtin_amdgcn_mfma_f32_32x32x16_bf16(afrag[0][g], bfrag, acc0, 0, 0, 0);
        acc1 = __builtin_amdgcn_mfma_f32_32x32x16_bf16(afrag[1][g], bfrag, acc1, 0, 0, 0);
    }
    __syncthreads();

    // ---- write acc to LDS out-tile (bank = l31, conflict-free)
    #pragma unroll
    for (int r = 0; r < 16; ++r) {
        int crow = (r & 3) + 8 * (r >> 2) + 4 * lhi;
        lx[crow][jc]      = acc0[r];
        lx[crow + 32][jc] = acc1[r];
    }
    __syncthreads();

    // ---- cooperative store-out: ds_read_b128 -> nontemporal dwordx4
    if (jf4 < T4) {
        float* ob = out + (size_t)b * C_DIM * T_DIM;
        #pragma unroll
        for (int p = 0; p < 8; ++p) {
            int e = p * 8 + (t >> 5);
            f32x4 v = *(const f32x4*)&lx[e][cf4 * 4];
            __builtin_nontemporal_store(v, (f32x4*)(ob + (size_t)e * T_DIM + (size_t)jf4 * 4));
        }
    }
}

extern "C" void kernel_launch(void* const* d_in, const int* in_sizes, int n_in,
                              void* d_out, int out_size, void* d_ws, size_t ws_size,
                              hipStream_t stream) {
    const float* x     = (const float*)d_in[0];
    const float* Wq    = (const float*)d_in[1];
    const float* bq    = (const float*)d_in[2];
    const float* Wk    = (const float*)d_in[3];
    const float* bk    = (const float*)d_in[4];
    // d_in[5] = Wv, d_in[6] = bv: dead code in the reference
    const float* alpha = (const float*)d_in[7];
    float* out = (float*)d_out;

    float* desc = (float*)d_ws;                                       // 8 KB
    unsigned short* attnb = (unsigned short*)(desc + ROWS);           // 256 KB bf16

    mean_kernel<<<ROWS, 256, 0, stream>>>(x, desc);
    attn_kernel<<<B_DIM, 64, 0, stream>>>(desc, Wq, bq, Wk, bk, alpha, attnb);
    mix_mfma<<<NWG, 256, 0, stream>>>(x, attnb, out);
}

// Round 10
// 123.856 us; speedup vs baseline: 1.2457x; 1.2457x over previous
//
#include <hip/hip_runtime.h>

#define B_DIM 32
#define C_DIM 64
#define D_DIM 64
#define T_DIM 30000
#define T4    7500
#define JTILE 128                 // floats of j per block (4 waves x 32)
#define TILES 235                 // ceil(30000 / 128)
#define NWG   (TILES * B_DIM)     // 7520, divisible by 8

typedef short bf16x8 __attribute__((ext_vector_type(8)));
typedef float f32x16 __attribute__((ext_vector_type(16)));
typedef float f32x4  __attribute__((ext_vector_type(4)));

__device__ __forceinline__ unsigned short f32_to_bf16_rne(float f) {
    unsigned int u = __builtin_bit_cast(unsigned int, f);
    return (unsigned short)((u + 0x7fffu + ((u >> 16) & 1u)) >> 16);
}

// ---------------- Kernel A: desc[b,c] = mean over T ----------------
__global__ __launch_bounds__(256) void mean_kernel(const float* __restrict__ x,
                                                   float* __restrict__ desc) {
    int r = blockIdx.x;  // b*64 + c
    const float4* xr = (const float4*)(x + (size_t)r * T_DIM);
    float4 s = {0.f, 0.f, 0.f, 0.f};
    for (int i = threadIdx.x; i < T4; i += 256) {
        float4 v = xr[i];
        s.x += v.x; s.y += v.y; s.z += v.z; s.w += v.w;
    }
    float p = (s.x + s.y) + (s.z + s.w);
    #pragma unroll
    for (int off = 32; off > 0; off >>= 1) p += __shfl_down(p, off, 64);
    __shared__ float wsum[4];
    int wave = threadIdx.x >> 6;
    int lane = threadIdx.x & 63;
    if (lane == 0) wsum[wave] = p;
    __syncthreads();
    if (threadIdx.x == 0) {
        float tot = (wsum[0] + wsum[1]) + (wsum[2] + wsum[3]);
        desc[r] = tot * (1.0f / (float)T_DIM);
    }
}

// ---------------- Kernel B: attn2 = bf16(alpha * softmax(logits) + I) ----------------
__global__ __launch_bounds__(64) void attn_kernel(const float* __restrict__ desc,
                                                  const float* __restrict__ Wq,
                                                  const float* __restrict__ bq,
                                                  const float* __restrict__ Wk,
                                                  const float* __restrict__ bk,
                                                  const float* __restrict__ alphap,
                                                  unsigned short* __restrict__ attnb) {
    int b = blockIdx.x;
    int c = threadIdx.x;
    __shared__ float sd[C_DIM];
    sd[c] = desc[b * C_DIM + c];
    __syncthreads();

    float dA = 0.f, dBq = 0.f, dBk = 0.f, dCc = 0.f;
    #pragma unroll
    for (int d = 0; d < D_DIM; ++d) {
        float wq = Wq[d], wk = Wk[d], vq = bq[d], vk = bk[d];
        dA  += wq * wk;
        dBq += wq * vk;
        dBk += vq * wk;
        dCc += vq * vk;
    }

    float dc = sd[c];
    float l[C_DIM];
    float lmax = -1e30f;
    #pragma unroll
    for (int e = 0; e < C_DIM; ++e) {
        float de = sd[e];
        float v = (dA * dc * de + dBq * dc + dBk * de + dCc) * 0.125f;
        l[e] = v;
        lmax = fmaxf(lmax, v);
    }
    float sum = 0.f;
    #pragma unroll
    for (int e = 0; e < C_DIM; ++e) {
        float ev = __expf(l[e] - lmax);
        l[e] = ev;
        sum += ev;
    }
    float inv = alphap[0] / sum;   // fold alpha
    unsigned short* arow = attnb + ((size_t)b * C_DIM + c) * C_DIM;
    #pragma unroll
    for (int e = 0; e < C_DIM; ++e) {
        float v = l[e] * inv + (e == c ? 1.0f : 0.0f);  // fold residual
        arow[e] = f32_to_bf16_rne(v);
    }
}

// ---------------- Kernel C: out = attn2 @ x via bf16 MFMA, LDS-staged ----------------
// Block = 4 waves, JTILE=128 j-cols. LDS x-tile f32 [64][128] (32 KB), reused
// for the output tile. All LDS access patterns have bank == (l&31): conflict-free.
__global__ __launch_bounds__(256) void mix_mfma(const float* __restrict__ x,
                                                const unsigned short* __restrict__ attnb,
                                                float* __restrict__ out) {
    __shared__ float lx[C_DIM][JTILE];   // 32 KB; x-tile, then out-tile

    // chunked XCD swizzle: same-b adjacent tiles stay on one XCD's L2
    int flat = blockIdx.x;
    int swz  = (flat & 7) * (NWG / 8) + (flat >> 3);
    int b    = swz / TILES;
    int tile = swz % TILES;

    int t   = threadIdx.x;
    int w   = t >> 6;
    int l31 = t & 31;
    int lhi = (t >> 5) & 1;

    // ---- A fragments (attn2, bf16) — issue first, fly under the staging barrier
    const unsigned short* ab = attnb + (size_t)b * C_DIM * C_DIM;
    bf16x8 afrag[2][4];
    #pragma unroll
    for (int m = 0; m < 2; ++m)
        #pragma unroll
        for (int g = 0; g < 4; ++g)
            afrag[m][g] = *(const bf16x8*)(ab + (32 * m + l31) * C_DIM + 16 * g + 8 * lhi);

    // ---- stage x tile: 8 coalesced float4 loads -> ds_write_b128
    const float* xb = x + (size_t)b * C_DIM * T_DIM;
    int cf4  = t & 31;                 // float4 col within tile
    int jf4  = tile * 32 + cf4;        // global float4 col
    int jf4c = (jf4 < T4) ? jf4 : (T4 - 1);
    #pragma unroll
    for (int p = 0; p < 8; ++p) {
        int e = p * 8 + (t >> 5);
        f32x4 v = *(const f32x4*)(xb + (size_t)e * T_DIM + (size_t)jf4c * 4);
        *(f32x4*)&lx[e][cf4 * 4] = v;
    }
    __syncthreads();

    // ---- compute: B-frags from LDS (conflict-free ds_read_b32), cvt, MFMA
    int jc = w * 32 + l31;             // this lane's j col within tile
    f32x16 acc0 = {}, acc1 = {};
    #pragma unroll
    for (int g = 0; g < 4; ++g) {
        int e0 = 16 * g + 8 * lhi;
        bf16x8 bfrag;
        #pragma unroll
        for (int i = 0; i < 8; ++i)
            bfrag[i] = (short)f32_to_bf16_rne(lx[e0 + i][jc]);
        acc0 = __builtin_amdgcn_mfma_f32_32x32x16_bf16(afrag[0][g], bfrag, acc0, 0, 0, 0);
        acc1 = __builtin_amdgcn_mfma_f32_32x32x16_bf16(afrag[1][g], bfrag, acc1, 0, 0, 0);
    }
    __syncthreads();

    // ---- write acc to LDS out-tile (bank = l31, conflict-free)
    #pragma unroll
    for (int r = 0; r < 16; ++r) {
        int crow = (r & 3) + 8 * (r >> 2) + 4 * lhi;
        lx[crow][jc]      = acc0[r];
        lx[crow + 32][jc] = acc1[r];
    }
    __syncthreads();

    // ---- cooperative store-out: ds_read_b128 -> nontemporal dwordx4
    if (jf4 < T4) {
        float* ob = out + (size_t)b * C_DIM * T_DIM;
        #pragma unroll
        for (int p = 0; p < 8; ++p) {
            int e = p * 8 + (t >> 5);
            f32x4 v = *(const f32x4*)&lx[e][cf4 * 4];
            __builtin_nontemporal_store(v, (f32x4*)(ob + (size_t)e * T_DIM + (size_t)jf4 * 4));
        }
    }
}

extern "C" void kernel_launch(void* const* d_in, const int* in_sizes, int n_in,
                              void* d_out, int out_size, void* d_ws, size_t ws_size,
                              hipStream_t stream) {
    const float* x     = (const float*)d_in[0];
    const float* Wq    = (const float*)d_in[1];
    const float* bq    = (const float*)d_in[2];
    const float* Wk    = (const float*)d_in[3];
    const float* bk    = (const float*)d_in[4];
    // d_in[5] = Wv, d_in[6] = bv: dead code in the reference
    const float* alpha = (const float*)d_in[7];
    float* out = (float*)d_out;

    float* desc = (float*)d_ws;                              // B*C floats (8 KB)
    unsigned short* attnb = (unsigned short*)(desc + B_DIM * C_DIM);  // B*C*C bf16 (256 KB)

    mean_kernel<<<B_DIM * C_DIM, 256, 0, stream>>>(x, desc);
    attn_kernel<<<B_DIM, 64, 0, stream>>>(desc, Wq, bq, Wk, bk, alpha, attnb);
    mix_mfma<<<NWG, 256, 0, stream>>>(x, attnb, out);
}